// Round 1
// baseline (8799.538 us; speedup 1.0000x reference)
//
#include <hip/hip_runtime.h>
#include <math.h>

#define B_ 32
#define N_ 1023
#define E_ 256
#define H_ 512
#define V_ 32000
#define T_ 64
#define NBL 500   // V_/64 logits blocks

__device__ __forceinline__ float sigf(float x) { return 1.0f / (1.0f + expf(-x)); }

// ---------------------------------------------------------------------------
// Tree iou GEMM: C[r][v] = sum_k A[r][k] * Wcat[k][v]
//   A[r][k] = k < 256 ? emb[tok(r)][k]*mask(r) : h[left]+h[right]
//   Wcat    = [W_iou (256x1536) ; U_iou (512x1536)]
// 128x128 tile, 8x8 micro, K-slice 8, 256 threads.
// ---------------------------------------------------------------------------
template<bool LEAF>
__global__ void __launch_bounds__(256)
iou_gemm_k(const int* __restrict__ node_feat, const int* __restrict__ mask,
           const float* __restrict__ emb, const float* __restrict__ Wiou,
           const float* __restrict__ Uiou, const float* __restrict__ hbuf,
           float* __restrict__ iou_out, int first, int n, int nshift)
{
    const int rows = B_ * n;
    const int K = LEAF ? E_ : (E_ + H_);
    const int rt = blockIdx.x, ct = blockIdx.y;
    const int tid = threadIdx.x;
    const int tr = tid >> 4, tc = tid & 15;

    __shared__ __align__(16) float As[8][136];
    __shared__ __align__(16) float Bs[8][136];

    float acc[8][8];
#pragma unroll
    for (int i = 0; i < 8; ++i)
#pragma unroll
        for (int j = 0; j < 8; ++j) acc[i][j] = 0.0f;

    const int lrow = tid >> 1;
    const int lkq  = (tid & 1) << 2;
    const int grow = rt * 128 + lrow;
    const bool rvalid = grow < rows;
    int tok = 0; float mval = 0.0f; int hoff1 = 0, hoff2 = 0;
    if (rvalid) {
        const int b = grow >> nshift, j = grow & (n - 1);
        const int node = first + j;
        tok  = node_feat[b * N_ + node];
        mval = (float)mask[b * N_ + node];
        if (!LEAF) {
            hoff1 = (b * N_ + 2 * node + 1) * H_;
            hoff2 = hoff1 + H_;
        }
    }
    const int bk   = tid >> 5;
    const int bcol = (tid & 31) << 2;
    const int gcol = ct * 128 + bcol;

    const int nkt = K >> 3;
    for (int kt = 0; kt < nkt; ++kt) {
        const int k0 = kt << 3;
        {   // A stage (gathered)
            const int kg = k0 + lkq;
            float4 v = make_float4(0.f, 0.f, 0.f, 0.f);
            if (rvalid) {
                if (LEAF || kg < E_) {
                    float4 e = *(const float4*)(emb + tok * E_ + kg);
                    v.x = e.x * mval; v.y = e.y * mval; v.z = e.z * mval; v.w = e.w * mval;
                } else {
                    const int kk = kg - E_;
                    float4 h1 = *(const float4*)(hbuf + hoff1 + kk);
                    float4 h2 = *(const float4*)(hbuf + hoff2 + kk);
                    v.x = h1.x + h2.x; v.y = h1.y + h2.y;
                    v.z = h1.z + h2.z; v.w = h1.w + h2.w;
                }
            }
            As[lkq + 0][lrow] = v.x;
            As[lkq + 1][lrow] = v.y;
            As[lkq + 2][lrow] = v.z;
            As[lkq + 3][lrow] = v.w;
        }
        {   // B stage
            const int kg = k0 + bk;
            const float* src = (LEAF || kg < E_) ? (Wiou + kg * 1536 + gcol)
                                                 : (Uiou + (kg - E_) * 1536 + gcol);
            *(float4*)&Bs[bk][bcol] = *(const float4*)src;
        }
        __syncthreads();
#pragma unroll
        for (int kk = 0; kk < 8; ++kk) {
            float a[8], bb[8];
            *(float4*)&a[0]  = *(const float4*)&As[kk][tr << 3];
            *(float4*)&a[4]  = *(const float4*)&As[kk][(tr << 3) + 4];
            *(float4*)&bb[0] = *(const float4*)&Bs[kk][tc << 2];
            *(float4*)&bb[4] = *(const float4*)&Bs[kk][(tc << 2) + 64];
#pragma unroll
            for (int i = 0; i < 8; ++i)
#pragma unroll
                for (int j = 0; j < 8; ++j)
                    acc[i][j] = fmaf(a[i], bb[j], acc[i][j]);
        }
        __syncthreads();
    }
#pragma unroll
    for (int i = 0; i < 8; ++i) {
        const int r = rt * 128 + (tr << 3) + i;
        if (r < rows) {
            float* dst = iou_out + (size_t)r * 1536 + ct * 128;
            *(float4*)(dst + (tc << 2))      = make_float4(acc[i][0], acc[i][1], acc[i][2], acc[i][3]);
            *(float4*)(dst + 64 + (tc << 2)) = make_float4(acc[i][4], acc[i][5], acc[i][6], acc[i][7]);
        }
    }
}

// ---------------------------------------------------------------------------
// f-gate GEMM with fused c_agg epilogue:
//   rows r=(b*n+j)*2+s ; A[r][k]=h[child_s][k] ; B=U_f_w
//   epilogue: c_agg[bj][col] = sig(f0+b)*c[ch0] + sig(f1+b)*c[ch1]
// Row pairs (s=0,1) land in the same thread's 8-row micro-tile.
// ---------------------------------------------------------------------------
__global__ void __launch_bounds__(256)
fagg_gemm_k(const float* __restrict__ hbuf, const float* __restrict__ cbuf,
            const float* __restrict__ Ufw, const float* __restrict__ Ufb,
            float* __restrict__ cagg, int first, int n, int nshift)
{
    const int rows = 64 * n;
    const int rt = blockIdx.x, ct = blockIdx.y;
    const int tid = threadIdx.x;
    const int tr = tid >> 4, tc = tid & 15;

    __shared__ __align__(16) float As[8][136];
    __shared__ __align__(16) float Bs[8][136];

    float acc[8][8];
#pragma unroll
    for (int i = 0; i < 8; ++i)
#pragma unroll
        for (int j = 0; j < 8; ++j) acc[i][j] = 0.0f;

    const int lrow = tid >> 1;
    const int lkq  = (tid & 1) << 2;
    const int grow = rt * 128 + lrow;
    const bool rvalid = grow < rows;
    int hoff = 0;
    if (rvalid) {
        const int bj = grow >> 1, s = grow & 1;
        const int b = bj >> nshift, j = bj & (n - 1);
        const int node = first + j;
        hoff = (b * N_ + 2 * node + 1 + s) * H_;
    }
    const int bk   = tid >> 5;
    const int bcol = (tid & 31) << 2;
    const int gcol = ct * 128 + bcol;

    for (int kt = 0; kt < 64; ++kt) {
        const int k0 = kt << 3;
        {
            const int kg = k0 + lkq;
            float4 v = make_float4(0.f, 0.f, 0.f, 0.f);
            if (rvalid) v = *(const float4*)(hbuf + hoff + kg);
            As[lkq + 0][lrow] = v.x;
            As[lkq + 1][lrow] = v.y;
            As[lkq + 2][lrow] = v.z;
            As[lkq + 3][lrow] = v.w;
        }
        {
            const int kg = k0 + bk;
            *(float4*)&Bs[bk][bcol] = *(const float4*)(Ufw + kg * H_ + gcol);
        }
        __syncthreads();
#pragma unroll
        for (int kk = 0; kk < 8; ++kk) {
            float a[8], bb[8];
            *(float4*)&a[0]  = *(const float4*)&As[kk][tr << 3];
            *(float4*)&a[4]  = *(const float4*)&As[kk][(tr << 3) + 4];
            *(float4*)&bb[0] = *(const float4*)&Bs[kk][tc << 2];
            *(float4*)&bb[4] = *(const float4*)&Bs[kk][(tc << 2) + 64];
#pragma unroll
            for (int i = 0; i < 8; ++i)
#pragma unroll
                for (int j = 0; j < 8; ++j)
                    acc[i][j] = fmaf(a[i], bb[j], acc[i][j]);
        }
        __syncthreads();
    }
#pragma unroll
    for (int p = 0; p < 4; ++p) {
        const int r0 = rt * 128 + (tr << 3) + 2 * p;
        if (r0 < rows) {
            const int bj = r0 >> 1;
            const int b = bj >> nshift, j = bj & (n - 1);
            const int node = first + j;
            const float* c1 = cbuf + (b * N_ + 2 * node + 1) * H_ + ct * 128;
            const float* c2 = c1 + H_;
            float* dst = cagg + bj * H_ + ct * 128;
#pragma unroll
            for (int g = 0; g < 2; ++g) {
                const int off = (g ? 64 : 0) + (tc << 2);
                const int jb = g * 4;
                float4 cc1 = *(const float4*)(c1 + off);
                float4 cc2 = *(const float4*)(c2 + off);
                float4 bbv = *(const float4*)(Ufb + ct * 128 + off);
                float4 res;
                res.x = sigf(acc[2*p][jb+0] + bbv.x) * cc1.x + sigf(acc[2*p+1][jb+0] + bbv.x) * cc2.x;
                res.y = sigf(acc[2*p][jb+1] + bbv.y) * cc1.y + sigf(acc[2*p+1][jb+1] + bbv.y) * cc2.y;
                res.z = sigf(acc[2*p][jb+2] + bbv.z) * cc1.z + sigf(acc[2*p+1][jb+2] + bbv.z) * cc2.z;
                res.w = sigf(acc[2*p][jb+3] + bbv.w) * cc1.w + sigf(acc[2*p+1][jb+3] + bbv.w) * cc2.w;
                *(float4*)(dst + off) = res;
            }
        }
    }
}

// ---------------------------------------------------------------------------
// apply_node: h,c update from iou (+b_iou) and c_agg
// ---------------------------------------------------------------------------
template<bool LEAF>
__global__ void apply_node_k(const float* __restrict__ iou,
                             const float* __restrict__ b_iou,
                             const float* __restrict__ cagg,
                             float* __restrict__ hbuf, float* __restrict__ cbuf,
                             int first, int n, int nshift)
{
    const int gid = blockIdx.x * 256 + threadIdx.x;
    if (gid >= B_ * n * 128) return;
    const int r = gid >> 7, col = (gid & 127) << 2;
    const float* row = iou + (size_t)r * 1536;
    float4 iv = *(const float4*)(row + col);
    float4 ov = *(const float4*)(row + 512 + col);
    float4 uv = *(const float4*)(row + 1024 + col);
    float4 bi = *(const float4*)(b_iou + col);
    float4 bo = *(const float4*)(b_iou + 512 + col);
    float4 bu = *(const float4*)(b_iou + 1024 + col);
    float4 ca = make_float4(0.f, 0.f, 0.f, 0.f);
    if (!LEAF) ca = *(const float4*)(cagg + r * H_ + col);
    float4 cn, hn;
    cn.x = sigf(iv.x + bi.x) * tanhf(uv.x + bu.x) + ca.x;
    cn.y = sigf(iv.y + bi.y) * tanhf(uv.y + bu.y) + ca.y;
    cn.z = sigf(iv.z + bi.z) * tanhf(uv.z + bu.z) + ca.z;
    cn.w = sigf(iv.w + bi.w) * tanhf(uv.w + bu.w) + ca.w;
    hn.x = sigf(ov.x + bo.x) * tanhf(cn.x);
    hn.y = sigf(ov.y + bo.y) * tanhf(cn.y);
    hn.z = sigf(ov.z + bo.z) * tanhf(cn.z);
    hn.w = sigf(ov.w + bo.w) * tanhf(cn.w);
    const int b = r >> nshift, j = r & (n - 1);
    const int node = first + j;
    const size_t o = (size_t)(b * N_ + node) * H_ + col;
    *(float4*)(cbuf + o) = cn;
    *(float4*)(hbuf + o) = hn;
}

// ---------------------------------------------------------------------------
// mean over nodes
// ---------------------------------------------------------------------------
__global__ void mean_k(const float* __restrict__ hbuf, float* __restrict__ mf)
{
    const int gid = blockIdx.x * 256 + threadIdx.x;   // 16384
    const int b = gid >> 9, k = gid & 511;
    float s = 0.f;
#pragma unroll 4
    for (int nn = 0; nn < N_; ++nn) s += hbuf[(b * N_ + nn) * H_ + k];
    mf[b * H_ + k] = s * (1.0f / (float)N_);
}

// hid/cel init GEMVs
__global__ void hidcel_k(const float* __restrict__ mf,
                         const float* __restrict__ hw, const float* __restrict__ hb,
                         const float* __restrict__ cw, const float* __restrict__ cb,
                         float* __restrict__ hs0, float* __restrict__ cs)
{
    const int gid = blockIdx.x * 256 + threadIdx.x;   // 32768
    const int which = gid >> 14;
    const int b = (gid >> 9) & 31, l = gid & 511;
    const float* W = which ? cw : hw;
    float acc = which ? cb[l] : hb[l];
#pragma unroll 8
    for (int k = 0; k < H_; ++k) acc = fmaf(mf[b * H_ + k], W[k * H_ + l], acc);
    if (which) cs[b * H_ + l] = acc; else hs0[b * H_ + l] = acc;
}

// ---------------------------------------------------------------------------
// decoder LSTM step: finalize prev argmax -> token -> gates -> hs,cs
// grid 64 blocks x 256 threads; block covers 8 l-values x 32 b
// ---------------------------------------------------------------------------
__global__ void __launch_bounds__(256)
lstm_step_k(const float* __restrict__ emb, const float* __restrict__ W_ih,
            const float* __restrict__ W_hh, const float* __restrict__ b_ih,
            const float* __restrict__ b_hh, const float* __restrict__ pval,
            const int* __restrict__ pidx, const float* __restrict__ hs_in,
            float* __restrict__ hs_out, float* __restrict__ cs, int t)
{
    __shared__ __align__(16) float xtS[E_ * 33];
    __shared__ __align__(16) float hsS[H_ * 33];
    __shared__ float rv[256];
    __shared__ int   ri[256];
    __shared__ int   tokS[B_];
    const int tid = threadIdx.x;

    if (t == 1) {
        if (tid < B_) tokS[tid] = 0;
    } else {
        const int b = tid & 31, ch = tid >> 5;
        float bv = -INFINITY; int bi2 = 0x7fffffff;
        for (int p = ch; p < NBL; p += 8) {
            const float v = pval[b * NBL + p];
            const int  ix = pidx[b * NBL + p];
            if (v > bv || (v == bv && ix < bi2)) { bv = v; bi2 = ix; }
        }
        rv[tid] = bv; ri[tid] = bi2;
        __syncthreads();
        if (tid < B_) {
            float Bv = -INFINITY; int Bi = 0x7fffffff;
#pragma unroll
            for (int c2 = 0; c2 < 8; ++c2) {
                const float v = rv[c2 * 32 + tid];
                const int  ix = ri[c2 * 32 + tid];
                if (v > Bv || (v == Bv && ix < Bi)) { Bv = v; Bi = ix; }
            }
            tokS[tid] = Bi;
        }
    }
    __syncthreads();

    for (int idx = tid; idx < B_ * E_; idx += 256) {
        const int b = idx >> 8, k = idx & 255;
        xtS[k * 33 + b] = emb[tokS[b] * E_ + k];
    }
    for (int idx = tid; idx < B_ * H_; idx += 256) {
        const int b = idx >> 9, k = idx & 511;
        hsS[k * 33 + b] = hs_in[b * H_ + k];
    }
    __syncthreads();

    const int b = tid & 31, li = tid >> 5;
    const int l = blockIdx.x * 8 + li;
    float ai = 0.f, af = 0.f, ag = 0.f, ao = 0.f;
#pragma unroll 8
    for (int k = 0; k < E_; ++k) {
        const float x = xtS[k * 33 + b];
        const float* w = W_ih + k * 2048 + l;
        ai = fmaf(x, w[0],    ai);
        af = fmaf(x, w[512],  af);
        ag = fmaf(x, w[1024], ag);
        ao = fmaf(x, w[1536], ao);
    }
#pragma unroll 8
    for (int k = 0; k < H_; ++k) {
        const float hv = hsS[k * 33 + b];
        const float* w = W_hh + k * 2048 + l;
        ai = fmaf(hv, w[0],    ai);
        af = fmaf(hv, w[512],  af);
        ag = fmaf(hv, w[1024], ag);
        ao = fmaf(hv, w[1536], ao);
    }
    ai += b_ih[l]        + b_hh[l];
    af += b_ih[512 + l]  + b_hh[512 + l];
    ag += b_ih[1024 + l] + b_hh[1024 + l];
    ao += b_ih[1536 + l] + b_hh[1536 + l];
    const float co = cs[b * H_ + l];
    const float cn = sigf(af) * co + sigf(ai) * tanhf(ag);
    cs[b * H_ + l] = cn;
    hs_out[b * H_ + l] = sigf(ao) * tanhf(cn);
}

// ---------------------------------------------------------------------------
// logits GEMM + bias + store + per-block argmax partials
// grid 500 x 256; block = 64 cols, thread = 4 cols x 8 b, kq-split 4
// ---------------------------------------------------------------------------
__global__ void __launch_bounds__(256)
logits_k(const float* __restrict__ fc_w, const float* __restrict__ fc_b,
         const float* __restrict__ hs, float* __restrict__ out_t,
         float* __restrict__ pval, int* __restrict__ pidx)
{
    __shared__ __align__(16) float smem[H_ * 36];   // hs staged [k][b] stride 36, reused for reductions
    __shared__ float avV[256];
    __shared__ int   avI[256];
    const int tid = threadIdx.x;
    const int blk = blockIdx.x;

    for (int idx = tid; idx < B_ * H_; idx += 256) {
        const int b = idx >> 9, k = idx & 511;
        smem[k * 36 + b] = hs[b * H_ + k];
    }
    __syncthreads();

    const int cg = tid & 15, bg = (tid >> 4) & 3, kq = tid >> 6;
    const int colbase = blk * 64 + (cg << 2);
    float acc[8][4];
#pragma unroll
    for (int i = 0; i < 8; ++i)
#pragma unroll
        for (int j = 0; j < 4; ++j) acc[i][j] = 0.f;

    const float* wp = fc_w + (kq * 128) * V_ + colbase;
    const float* hp = smem + (kq * 128) * 36 + (bg << 3);
#pragma unroll 4
    for (int kk = 0; kk < 128; ++kk) {
        float4 w4 = *(const float4*)wp; wp += V_;
        float hv[8];
        *(float4*)&hv[0] = *(const float4*)hp;
        *(float4*)&hv[4] = *(const float4*)(hp + 4);
        hp += 36;
        float wv[4] = {w4.x, w4.y, w4.z, w4.w};
#pragma unroll
        for (int i = 0; i < 8; ++i)
#pragma unroll
            for (int j = 0; j < 4; ++j)
                acc[i][j] = fmaf(hv[i], wv[j], acc[i][j]);
    }
    __syncthreads();   // all hsS reads done; reuse smem

    float* redS = smem;          // [kq][b][col] : 4*32*64
#pragma unroll
    for (int i = 0; i < 8; ++i)
#pragma unroll
        for (int j = 0; j < 4; ++j)
            redS[kq * 2048 + ((bg << 3) + i) * 64 + (cg << 2) + j] = acc[i][j];
    __syncthreads();

    float* amaxS = smem + 8192;  // [b][col] : 32*64
    {
        const int col = tid & 63, bq = tid >> 6;
#pragma unroll
        for (int f = 0; f < 8; ++f) {
            const int b = (bq << 3) + f;
            float v = redS[b * 64 + col] + redS[2048 + b * 64 + col]
                    + redS[4096 + b * 64 + col] + redS[6144 + b * 64 + col];
            v += fc_b[blk * 64 + col];
            out_t[b * V_ + blk * 64 + col] = v;
            amaxS[b * 64 + col] = v;
        }
    }
    __syncthreads();
    {
        const int b = tid & 31, ch = tid >> 5;
        float bv = -INFINITY; int bi = 0;
#pragma unroll
        for (int j = 0; j < 8; ++j) {
            const float v = amaxS[b * 64 + (ch << 3) + j];
            if (v > bv) { bv = v; bi = (ch << 3) + j; }
        }
        avV[tid] = bv; avI[tid] = bi;
    }
    __syncthreads();
    if (tid < B_) {
        float bv = -INFINITY; int bi = 0;
#pragma unroll
        for (int ch = 0; ch < 8; ++ch) {
            const float v = avV[ch * 32 + tid];
            if (v > bv) { bv = v; bi = avI[ch * 32 + tid]; }
        }
        pval[tid * NBL + blk] = bv;
        pidx[tid * NBL + blk] = blk * 64 + bi;
    }
}

// ---------------------------------------------------------------------------
extern "C" void kernel_launch(void* const* d_in, const int* in_sizes, int n_in,
                              void* d_out, int out_size, void* d_ws, size_t ws_size,
                              hipStream_t stream)
{
    (void)in_sizes; (void)n_in; (void)out_size; (void)ws_size;
    const int*   node_feat = (const int*)  d_in[0];
    const int*   mask      = (const int*)  d_in[1];
    const float* emb       = (const float*)d_in[2];
    const float* W_iou     = (const float*)d_in[3];
    const float* U_iou     = (const float*)d_in[4];
    const float* b_iou     = (const float*)d_in[5];
    const float* U_f_w     = (const float*)d_in[6];
    const float* U_f_b     = (const float*)d_in[7];
    const float* hid_fc_w  = (const float*)d_in[8];
    const float* hid_fc_b  = (const float*)d_in[9];
    const float* cell_fc_w = (const float*)d_in[10];
    const float* cell_fc_b = (const float*)d_in[11];
    const float* W_ih      = (const float*)d_in[12];
    const float* W_hh      = (const float*)d_in[13];
    const float* b_ih      = (const float*)d_in[14];
    const float* b_hh      = (const float*)d_in[15];
    const float* fc_w      = (const float*)d_in[16];
    const float* fc_b      = (const float*)d_in[17];
    float* out = (float*)d_out;

    float* ws      = (float*)d_ws;
    float* iou_buf = ws;                      // 12,582,912 (8192 x 1536)
    float* cagg    = ws + 12582912;           //  4,194,304 (8192 x 512)
    float* hbuf    = ws + 16777216;           // 16,760,832
    float* cbuf    = ws + 33538048;           // 16,760,832
    float* mf      = ws + 50298880;           //     16,384
    float* hsb     = ws + 50315264;           //     32,768 (ping-pong)
    float* csb     = ws + 50348032;           //     16,384
    float* pval    = ws + 50364416;           //     16,000
    int*   pidx    = (int*)(ws + 50380416);   //     16,000

    // ---- tree: leaves (2 chunks of 256 nodes) ----
    for (int chunk = 0; chunk < 2; ++chunk) {
        const int first = 511 + 256 * chunk;
        dim3 g(64, 12);
        iou_gemm_k<true><<<g, 256, 0, stream>>>(node_feat, mask, emb, W_iou, U_iou,
                                                hbuf, iou_buf, first, 256, 8);
        apply_node_k<true><<<4096, 256, 0, stream>>>(iou_buf, b_iou, cagg,
                                                     hbuf, cbuf, first, 256, 8);
    }
    // ---- tree: internal levels ----
    for (int d = 8; d >= 0; --d) {
        const int n = 1 << d, first = n - 1;
        dim3 gf((64 * n + 127) / 128, 4);
        fagg_gemm_k<<<gf, 256, 0, stream>>>(hbuf, cbuf, U_f_w, U_f_b, cagg, first, n, d);
        dim3 gi((32 * n + 127) / 128, 12);
        iou_gemm_k<false><<<gi, 256, 0, stream>>>(node_feat, mask, emb, W_iou, U_iou,
                                                  hbuf, iou_buf, first, n, d);
        apply_node_k<false><<<16 * n, 256, 0, stream>>>(iou_buf, b_iou, cagg,
                                                        hbuf, cbuf, first, n, d);
    }
    // ---- pool + init ----
    mean_k<<<64, 256, 0, stream>>>(hbuf, mf);
    hidcel_k<<<128, 256, 0, stream>>>(mf, hid_fc_w, hid_fc_b, cell_fc_w, cell_fc_b, hsb, csb);
    // ---- out[0] = 0 ----
    hipMemsetAsync(d_out, 0, (size_t)B_ * V_ * sizeof(float), stream);
    // ---- decoder ----
    for (int t = 1; t < T_; ++t) {
        const float* hs_in  = hsb + ((t - 1) & 1) * (B_ * H_);
        float*       hs_out = hsb + (t & 1) * (B_ * H_);
        lstm_step_k<<<64, 256, 0, stream>>>(emb, W_ih, W_hh, b_ih, b_hh,
                                            pval, pidx, hs_in, hs_out, csb, t);
        logits_k<<<NBL, 256, 0, stream>>>(fc_w, fc_b, hs_out,
                                          out + (size_t)t * B_ * V_, pval, pidx);
    }
}

// Round 3
// 6559.666 us; speedup vs baseline: 1.3415x; 1.3415x over previous
//
#include <hip/hip_runtime.h>
#include <math.h>

#define B_ 32
#define N_ 1023
#define E_ 256
#define H_ 512
#define V_ 32000
#define T_ 64
#define NBL 250   // V_/128 logits blocks

__device__ __forceinline__ float sigf(float x) { return 1.0f / (1.0f + expf(-x)); }

// ---------------------------------------------------------------------------
// Tree iou GEMM: C[r][v] = sum_k A[r][k] * Wcat[k][v]
//   A[r][k] = k < 256 ? emb[tok(r)][k]*mask(r) : h[left]+h[right]
//   Wcat    = [W_iou (256x1536) ; U_iou (512x1536)]
// 128x128 tile, 8x8 micro, K-slice 8, 256 threads.
// ---------------------------------------------------------------------------
template<bool LEAF>
__global__ void __launch_bounds__(256)
iou_gemm_k(const int* __restrict__ node_feat, const int* __restrict__ mask,
           const float* __restrict__ emb, const float* __restrict__ Wiou,
           const float* __restrict__ Uiou, const float* __restrict__ hbuf,
           float* __restrict__ iou_out, int first, int n, int nshift)
{
    const int rows = B_ * n;
    const int K = LEAF ? E_ : (E_ + H_);
    const int rt = blockIdx.x, ct = blockIdx.y;
    const int tid = threadIdx.x;
    const int tr = tid >> 4, tc = tid & 15;

    __shared__ __align__(16) float As[8][136];
    __shared__ __align__(16) float Bs[8][136];

    float acc[8][8];
#pragma unroll
    for (int i = 0; i < 8; ++i)
#pragma unroll
        for (int j = 0; j < 8; ++j) acc[i][j] = 0.0f;

    const int lrow = tid >> 1;
    const int lkq  = (tid & 1) << 2;
    const int grow = rt * 128 + lrow;
    const bool rvalid = grow < rows;
    int tok = 0; float mval = 0.0f; int hoff1 = 0, hoff2 = 0;
    if (rvalid) {
        const int b = grow >> nshift, j = grow & (n - 1);
        const int node = first + j;
        tok  = node_feat[b * N_ + node];
        mval = (float)mask[b * N_ + node];
        if (!LEAF) {
            hoff1 = (b * N_ + 2 * node + 1) * H_;
            hoff2 = hoff1 + H_;
        }
    }
    const int bk   = tid >> 5;
    const int bcol = (tid & 31) << 2;
    const int gcol = ct * 128 + bcol;

    const int nkt = K >> 3;
    for (int kt = 0; kt < nkt; ++kt) {
        const int k0 = kt << 3;
        {   // A stage (gathered)
            const int kg = k0 + lkq;
            float4 v = make_float4(0.f, 0.f, 0.f, 0.f);
            if (rvalid) {
                if (LEAF || kg < E_) {
                    float4 e = *(const float4*)(emb + tok * E_ + kg);
                    v.x = e.x * mval; v.y = e.y * mval; v.z = e.z * mval; v.w = e.w * mval;
                } else {
                    const int kk = kg - E_;
                    float4 h1 = *(const float4*)(hbuf + hoff1 + kk);
                    float4 h2 = *(const float4*)(hbuf + hoff2 + kk);
                    v.x = h1.x + h2.x; v.y = h1.y + h2.y;
                    v.z = h1.z + h2.z; v.w = h1.w + h2.w;
                }
            }
            As[lkq + 0][lrow] = v.x;
            As[lkq + 1][lrow] = v.y;
            As[lkq + 2][lrow] = v.z;
            As[lkq + 3][lrow] = v.w;
        }
        {   // B stage
            const int kg = k0 + bk;
            const float* src = (LEAF || kg < E_) ? (Wiou + kg * 1536 + gcol)
                                                 : (Uiou + (kg - E_) * 1536 + gcol);
            *(float4*)&Bs[bk][bcol] = *(const float4*)src;
        }
        __syncthreads();
#pragma unroll
        for (int kk = 0; kk < 8; ++kk) {
            float a[8], bb[8];
            *(float4*)&a[0]  = *(const float4*)&As[kk][tr << 3];
            *(float4*)&a[4]  = *(const float4*)&As[kk][(tr << 3) + 4];
            *(float4*)&bb[0] = *(const float4*)&Bs[kk][tc << 2];
            *(float4*)&bb[4] = *(const float4*)&Bs[kk][(tc << 2) + 64];
#pragma unroll
            for (int i = 0; i < 8; ++i)
#pragma unroll
                for (int j = 0; j < 8; ++j)
                    acc[i][j] = fmaf(a[i], bb[j], acc[i][j]);
        }
        __syncthreads();
    }
#pragma unroll
    for (int i = 0; i < 8; ++i) {
        const int r = rt * 128 + (tr << 3) + i;
        if (r < rows) {
            float* dst = iou_out + (size_t)r * 1536 + ct * 128;
            *(float4*)(dst + (tc << 2))      = make_float4(acc[i][0], acc[i][1], acc[i][2], acc[i][3]);
            *(float4*)(dst + 64 + (tc << 2)) = make_float4(acc[i][4], acc[i][5], acc[i][6], acc[i][7]);
        }
    }
}

// ---------------------------------------------------------------------------
// f-gate GEMM with fused c_agg epilogue.
// ---------------------------------------------------------------------------
__global__ void __launch_bounds__(256)
fagg_gemm_k(const float* __restrict__ hbuf, const float* __restrict__ cbuf,
            const float* __restrict__ Ufw, const float* __restrict__ Ufb,
            float* __restrict__ cagg, int first, int n, int nshift)
{
    const int rows = 64 * n;
    const int rt = blockIdx.x, ct = blockIdx.y;
    const int tid = threadIdx.x;
    const int tr = tid >> 4, tc = tid & 15;

    __shared__ __align__(16) float As[8][136];
    __shared__ __align__(16) float Bs[8][136];

    float acc[8][8];
#pragma unroll
    for (int i = 0; i < 8; ++i)
#pragma unroll
        for (int j = 0; j < 8; ++j) acc[i][j] = 0.0f;

    const int lrow = tid >> 1;
    const int lkq  = (tid & 1) << 2;
    const int grow = rt * 128 + lrow;
    const bool rvalid = grow < rows;
    int hoff = 0;
    if (rvalid) {
        const int bj = grow >> 1, s = grow & 1;
        const int b = bj >> nshift, j = bj & (n - 1);
        const int node = first + j;
        hoff = (b * N_ + 2 * node + 1 + s) * H_;
    }
    const int bk   = tid >> 5;
    const int bcol = (tid & 31) << 2;
    const int gcol = ct * 128 + bcol;

    for (int kt = 0; kt < 64; ++kt) {
        const int k0 = kt << 3;
        {
            const int kg = k0 + lkq;
            float4 v = make_float4(0.f, 0.f, 0.f, 0.f);
            if (rvalid) v = *(const float4*)(hbuf + hoff + kg);
            As[lkq + 0][lrow] = v.x;
            As[lkq + 1][lrow] = v.y;
            As[lkq + 2][lrow] = v.z;
            As[lkq + 3][lrow] = v.w;
        }
        {
            const int kg = k0 + bk;
            *(float4*)&Bs[bk][bcol] = *(const float4*)(Ufw + kg * H_ + gcol);
        }
        __syncthreads();
#pragma unroll
        for (int kk = 0; kk < 8; ++kk) {
            float a[8], bb[8];
            *(float4*)&a[0]  = *(const float4*)&As[kk][tr << 3];
            *(float4*)&a[4]  = *(const float4*)&As[kk][(tr << 3) + 4];
            *(float4*)&bb[0] = *(const float4*)&Bs[kk][tc << 2];
            *(float4*)&bb[4] = *(const float4*)&Bs[kk][(tc << 2) + 64];
#pragma unroll
            for (int i = 0; i < 8; ++i)
#pragma unroll
                for (int j = 0; j < 8; ++j)
                    acc[i][j] = fmaf(a[i], bb[j], acc[i][j]);
        }
        __syncthreads();
    }
#pragma unroll
    for (int p = 0; p < 4; ++p) {
        const int r0 = rt * 128 + (tr << 3) + 2 * p;
        if (r0 < rows) {
            const int bj = r0 >> 1;
            const int b = bj >> nshift, j = bj & (n - 1);
            const int node = first + j;
            const float* c1 = cbuf + (b * N_ + 2 * node + 1) * H_ + ct * 128;
            const float* c2 = c1 + H_;
            float* dst = cagg + bj * H_ + ct * 128;
#pragma unroll
            for (int g = 0; g < 2; ++g) {
                const int off = (g ? 64 : 0) + (tc << 2);
                const int jb = g * 4;
                float4 cc1 = *(const float4*)(c1 + off);
                float4 cc2 = *(const float4*)(c2 + off);
                float4 bbv = *(const float4*)(Ufb + ct * 128 + off);
                float4 res;
                res.x = sigf(acc[2*p][jb+0] + bbv.x) * cc1.x + sigf(acc[2*p+1][jb+0] + bbv.x) * cc2.x;
                res.y = sigf(acc[2*p][jb+1] + bbv.y) * cc1.y + sigf(acc[2*p+1][jb+1] + bbv.y) * cc2.y;
                res.z = sigf(acc[2*p][jb+2] + bbv.z) * cc1.z + sigf(acc[2*p+1][jb+2] + bbv.z) * cc2.z;
                res.w = sigf(acc[2*p][jb+3] + bbv.w) * cc1.w + sigf(acc[2*p+1][jb+3] + bbv.w) * cc2.w;
                *(float4*)(dst + off) = res;
            }
        }
    }
}

// ---------------------------------------------------------------------------
template<bool LEAF>
__global__ void apply_node_k(const float* __restrict__ iou,
                             const float* __restrict__ b_iou,
                             const float* __restrict__ cagg,
                             float* __restrict__ hbuf, float* __restrict__ cbuf,
                             int first, int n, int nshift)
{
    const int gid = blockIdx.x * 256 + threadIdx.x;
    if (gid >= B_ * n * 128) return;
    const int r = gid >> 7, col = (gid & 127) << 2;
    const float* row = iou + (size_t)r * 1536;
    float4 iv = *(const float4*)(row + col);
    float4 ov = *(const float4*)(row + 512 + col);
    float4 uv = *(const float4*)(row + 1024 + col);
    float4 bi = *(const float4*)(b_iou + col);
    float4 bo = *(const float4*)(b_iou + 512 + col);
    float4 bu = *(const float4*)(b_iou + 1024 + col);
    float4 ca = make_float4(0.f, 0.f, 0.f, 0.f);
    if (!LEAF) ca = *(const float4*)(cagg + r * H_ + col);
    float4 cn, hn;
    cn.x = sigf(iv.x + bi.x) * tanhf(uv.x + bu.x) + ca.x;
    cn.y = sigf(iv.y + bi.y) * tanhf(uv.y + bu.y) + ca.y;
    cn.z = sigf(iv.z + bi.z) * tanhf(uv.z + bu.z) + ca.z;
    cn.w = sigf(iv.w + bi.w) * tanhf(uv.w + bu.w) + ca.w;
    hn.x = sigf(ov.x + bo.x) * tanhf(cn.x);
    hn.y = sigf(ov.y + bo.y) * tanhf(cn.y);
    hn.z = sigf(ov.z + bo.z) * tanhf(cn.z);
    hn.w = sigf(ov.w + bo.w) * tanhf(cn.w);
    const int b = r >> nshift, j = r & (n - 1);
    const int node = first + j;
    const size_t o = (size_t)(b * N_ + node) * H_ + col;
    *(float4*)(cbuf + o) = cn;
    *(float4*)(hbuf + o) = hn;
}

// ---------------------------------------------------------------------------
__global__ void mean_k(const float* __restrict__ hbuf, float* __restrict__ mf)
{
    const int gid = blockIdx.x * 256 + threadIdx.x;   // 16384
    const int b = gid >> 9, k = gid & 511;
    float s = 0.f;
#pragma unroll 4
    for (int nn = 0; nn < N_; ++nn) s += hbuf[(b * N_ + nn) * H_ + k];
    mf[b * H_ + k] = s * (1.0f / (float)N_);
}

__global__ void hidcel_k(const float* __restrict__ mf,
                         const float* __restrict__ hw, const float* __restrict__ hb,
                         const float* __restrict__ cw, const float* __restrict__ cb,
                         float* __restrict__ hs0, float* __restrict__ cs)
{
    const int gid = blockIdx.x * 256 + threadIdx.x;   // 32768
    const int which = gid >> 14;
    const int b = (gid >> 9) & 31, l = gid & 511;
    const float* W = which ? cw : hw;
    float acc = which ? cb[l] : hb[l];
#pragma unroll 8
    for (int k = 0; k < H_; ++k) acc = fmaf(mf[b * H_ + k], W[k * H_ + l], acc);
    if (which) cs[b * H_ + l] = acc; else hs0[b * H_ + l] = acc;
}

// ---------------------------------------------------------------------------
// decoder LSTM step v3: 256 blocks x 2 l-cols; waves K-split (4 x (64 x-rows
// + 128 h-rows)); x/h staged in LDS xh[768][32]; LDS partial reduce.
// ---------------------------------------------------------------------------
__global__ void __launch_bounds__(256)
lstm_step_k(const float* __restrict__ emb, const float* __restrict__ W_ih,
            const float* __restrict__ W_hh, const float* __restrict__ b_ih,
            const float* __restrict__ b_hh, const float* __restrict__ pval,
            const int* __restrict__ pidx, const float* __restrict__ hs_in,
            float* __restrict__ hs_out, float* __restrict__ cs, int t)
{
    __shared__ __align__(16) float xh[768 * 32];   // 98.3 KB; reused for partials
    __shared__ float rv[256];
    __shared__ int   ri[256];
    __shared__ int   tokS[B_];
    const int tid = threadIdx.x;

    // ---- finalize previous step's argmax -> tokens ----
    if (t == 1) {
        if (tid < B_) tokS[tid] = 0;
    } else {
        const int b = tid & 31, ch = tid >> 5;
        float bv = -INFINITY; int bi2 = 0x7fffffff;
        for (int p = ch; p < NBL; p += 8) {
            const float v = pval[b * NBL + p];
            const int  ix = pidx[b * NBL + p];
            if (v > bv || (v == bv && ix < bi2)) { bv = v; bi2 = ix; }
        }
        rv[tid] = bv; ri[tid] = bi2;
        __syncthreads();
        if (tid < B_) {
            float Bv = -INFINITY; int Bi = 0x7fffffff;
#pragma unroll
            for (int c2 = 0; c2 < 8; ++c2) {
                const float v = rv[c2 * 32 + tid];
                const int  ix = ri[c2 * 32 + tid];
                if (v > Bv || (v == Bv && ix < Bi)) { Bv = v; Bi = ix; }
            }
            tokS[tid] = Bi;
        }
    }
    __syncthreads();

    // ---- stage x (emb gather) and hs into xh[k][b] ----
    for (int idx = tid; idx < B_ * E_; idx += 256) {
        const int b = idx >> 8, k = idx & 255;
        xh[k * 32 + b] = emb[tokS[b] * E_ + k];
    }
    for (int idx = tid; idx < B_ * H_; idx += 256) {
        const int b = idx >> 9, k = idx & 511;
        xh[(E_ + k) * 32 + b] = hs_in[b * H_ + k];
    }
    __syncthreads();

    // ---- K-split gate partials ----
    const int b  = tid & 31;
    const int li = (tid >> 5) & 1;
    const int kq = tid >> 6;
    const int l  = blockIdx.x * 2 + li;
    float ai = 0.f, af = 0.f, ag = 0.f, ao = 0.f;
    {   // x part: rows [kq*64, kq*64+64)
        const float* w  = W_ih + (kq * 64) * 2048 + l;
        const float* xp = xh + (kq * 64) * 32 + b;
#pragma unroll 8
        for (int k = 0; k < 64; ++k) {
            const float x = xp[k * 32];
            ai = fmaf(x, w[0],    ai);
            af = fmaf(x, w[512],  af);
            ag = fmaf(x, w[1024], ag);
            ao = fmaf(x, w[1536], ao);
            w += 2048;
        }
    }
    {   // h part: rows [kq*128, kq*128+128)
        const float* w  = W_hh + (kq * 128) * 2048 + l;
        const float* xp = xh + (E_ + kq * 128) * 32 + b;
#pragma unroll 8
        for (int k = 0; k < 128; ++k) {
            const float x = xp[k * 32];
            ai = fmaf(x, w[0],    ai);
            af = fmaf(x, w[512],  af);
            ag = fmaf(x, w[1024], ag);
            ao = fmaf(x, w[1536], ao);
            w += 2048;
        }
    }
    __syncthreads();           // all xh reads done; reuse as partial buffer
    {
        const int slot = ((kq * 2 + li) * 32 + b) * 4;
        xh[slot + 0] = ai; xh[slot + 1] = af;
        xh[slot + 2] = ag; xh[slot + 3] = ao;
    }
    __syncthreads();
    if (tid < 64) {
        const int b2 = tid & 31, li2 = tid >> 5;
        const int l2 = blockIdx.x * 2 + li2;
        float s0 = 0.f, s1 = 0.f, s2 = 0.f, s3 = 0.f;
#pragma unroll
        for (int q = 0; q < 4; ++q) {
            const int sl = ((q * 2 + li2) * 32 + b2) * 4;
            s0 += xh[sl + 0]; s1 += xh[sl + 1];
            s2 += xh[sl + 2]; s3 += xh[sl + 3];
        }
        const float gi = s0 + b_ih[l2]        + b_hh[l2];
        const float gf = s1 + b_ih[512 + l2]  + b_hh[512 + l2];
        const float gg = s2 + b_ih[1024 + l2] + b_hh[1024 + l2];
        const float go = s3 + b_ih[1536 + l2] + b_hh[1536 + l2];
        const float co = cs[b2 * H_ + l2];
        const float cn = sigf(gf) * co + sigf(gi) * tanhf(gg);
        cs[b2 * H_ + l2] = cn;
        hs_out[b2 * H_ + l2] = sigf(go) * tanhf(cn);
    }
}

// ---------------------------------------------------------------------------
// logits v2: 250 blocks x 128 cols. Waves split K (kq=0..3, 128 rows each);
// lane owns 2 cols, acc[32 b][2]. w-loads 512B contiguous/wave; hs reads are
// wave-uniform LDS broadcasts. K-partials reduced via reused LDS.
// ---------------------------------------------------------------------------
__global__ void __launch_bounds__(256)
logits_k(const float* __restrict__ fc_w, const float* __restrict__ fc_b,
         const float* __restrict__ hs, float* __restrict__ out_t,
         float* __restrict__ pval, int* __restrict__ pidx)
{
    __shared__ __align__(16) float smem[H_ * 36];   // 73.7 KB, reused
    __shared__ float rv[256];
    __shared__ int   ri[256];
    const int tid = threadIdx.x, blk = blockIdx.x;

    // stage hs -> smem[k][36] (b fast)
    for (int idx = tid; idx < B_ * H_; idx += 256) {
        const int b = idx >> 9, k = idx & 511;
        smem[k * 36 + b] = hs[b * H_ + k];
    }
    __syncthreads();

    const int kq   = tid >> 6;            // wave: k in [kq*128, kq*128+128)
    const int lane = tid & 63;
    const int col  = lane << 1;           // 2 cols/lane, 128 cols/block
    float acc[32][2];
#pragma unroll
    for (int bb = 0; bb < 32; ++bb) { acc[bb][0] = 0.f; acc[bb][1] = 0.f; }

    const float* wp = fc_w + (size_t)(kq * 128) * V_ + blk * 128 + col;
    const float* hp = smem + (kq * 128) * 36;
#pragma unroll 4
    for (int kk = 0; kk < 128; ++kk) {
        const float2 w2 = *(const float2*)wp; wp += V_;
        float hv[16];
        *(float4*)&hv[0]  = *(const float4*)(hp + 0);
        *(float4*)&hv[4]  = *(const float4*)(hp + 4);
        *(float4*)&hv[8]  = *(const float4*)(hp + 8);
        *(float4*)&hv[12] = *(const float4*)(hp + 12);
#pragma unroll
        for (int bb = 0; bb < 16; ++bb) {
            acc[bb][0] = fmaf(hv[bb], w2.x, acc[bb][0]);
            acc[bb][1] = fmaf(hv[bb], w2.y, acc[bb][1]);
        }
        *(float4*)&hv[0]  = *(const float4*)(hp + 16);
        *(float4*)&hv[4]  = *(const float4*)(hp + 20);
        *(float4*)&hv[8]  = *(const float4*)(hp + 24);
        *(float4*)&hv[12] = *(const float4*)(hp + 28);
#pragma unroll
        for (int bb = 0; bb < 16; ++bb) {
            acc[16 + bb][0] = fmaf(hv[bb], w2.x, acc[16 + bb][0]);
            acc[16 + bb][1] = fmaf(hv[bb], w2.y, acc[16 + bb][1]);
        }
        hp += 36;
    }
    __syncthreads();          // all hs reads complete; reuse smem

    // partials: redS[kq][b][132]
    float* redS = smem;
#pragma unroll
    for (int bb = 0; bb < 32; ++bb) {
        redS[kq * 4224 + bb * 132 + col]     = acc[bb][0];
        redS[kq * 4224 + bb * 132 + col + 1] = acc[bb][1];
    }
    __syncthreads();

    // reduce + bias + store + stash for argmax
    for (int idx = tid; idx < 4096; idx += 256) {
        const int c2 = idx & 127, b = idx >> 7;
        float v = redS[b * 132 + c2] + redS[4224 + b * 132 + c2]
                + redS[8448 + b * 132 + c2] + redS[12672 + b * 132 + c2]
                + fc_b[blk * 128 + c2];
        out_t[(size_t)b * V_ + blk * 128 + c2] = v;
        redS[b * 132 + c2] = v;   // owner slot, safe
    }
    __syncthreads();

    // block argmax partials
    {
        const int b = tid & 31, ch = tid >> 5;
        float bv = -INFINITY; int bi = 0;
#pragma unroll
        for (int j = 0; j < 16; ++j) {
            const int c2 = (ch << 4) + j;
            const float v = redS[b * 132 + c2];
            if (v > bv) { bv = v; bi = c2; }
        }
        rv[tid] = bv; ri[tid] = bi;
    }
    __syncthreads();
    if (tid < B_) {
        float bv = -INFINITY; int bi = 0;
#pragma unroll
        for (int ch = 0; ch < 8; ++ch) {
            const float v = rv[ch * 32 + tid];
            if (v > bv) { bv = v; bi = ri[ch * 32 + tid]; }
        }
        pval[tid * NBL + blk] = bv;
        pidx[tid * NBL + blk] = blk * 128 + bi;
    }
}

// ---------------------------------------------------------------------------
extern "C" void kernel_launch(void* const* d_in, const int* in_sizes, int n_in,
                              void* d_out, int out_size, void* d_ws, size_t ws_size,
                              hipStream_t stream)
{
    (void)in_sizes; (void)n_in; (void)out_size; (void)ws_size;
    const int*   node_feat = (const int*)  d_in[0];
    const int*   mask      = (const int*)  d_in[1];
    const float* emb       = (const float*)d_in[2];
    const float* W_iou     = (const float*)d_in[3];
    const float* U_iou     = (const float*)d_in[4];
    const float* b_iou     = (const float*)d_in[5];
    const float* U_f_w     = (const float*)d_in[6];
    const float* U_f_b     = (const float*)d_in[7];
    const float* hid_fc_w  = (const float*)d_in[8];
    const float* hid_fc_b  = (const float*)d_in[9];
    const float* cell_fc_w = (const float*)d_in[10];
    const float* cell_fc_b = (const float*)d_in[11];
    const float* W_ih      = (const float*)d_in[12];
    const float* W_hh      = (const float*)d_in[13];
    const float* b_ih      = (const float*)d_in[14];
    const float* b_hh      = (const float*)d_in[15];
    const float* fc_w      = (const float*)d_in[16];
    const float* fc_b      = (const float*)d_in[17];
    float* out = (float*)d_out;

    float* ws      = (float*)d_ws;
    float* iou_buf = ws;                      // 12,582,912 (8192 x 1536)
    float* cagg    = ws + 12582912;           //  4,194,304 (8192 x 512)
    float* hbuf    = ws + 16777216;           // 16,760,832
    float* cbuf    = ws + 33538048;           // 16,760,832
    float* mf      = ws + 50298880;           //     16,384
    float* hsb     = ws + 50315264;           //     32,768 (ping-pong)
    float* csb     = ws + 50348032;           //     16,384
    float* pval    = ws + 50364416;           //      8,000
    int*   pidx    = (int*)(ws + 50372416);   //      8,000

    // ---- tree: leaves (2 chunks of 256 nodes) ----
    for (int chunk = 0; chunk < 2; ++chunk) {
        const int first = 511 + 256 * chunk;
        dim3 g(64, 12);
        iou_gemm_k<true><<<g, 256, 0, stream>>>(node_feat, mask, emb, W_iou, U_iou,
                                                hbuf, iou_buf, first, 256, 8);
        apply_node_k<true><<<4096, 256, 0, stream>>>(iou_buf, b_iou, cagg,
                                                     hbuf, cbuf, first, 256, 8);
    }
    // ---- tree: internal levels ----
    for (int d = 8; d >= 0; --d) {
        const int n = 1 << d, first = n - 1;
        dim3 gf((64 * n + 127) / 128, 4);
        fagg_gemm_k<<<gf, 256, 0, stream>>>(hbuf, cbuf, U_f_w, U_f_b, cagg, first, n, d);
        dim3 gi((32 * n + 127) / 128, 12);
        iou_gemm_k<false><<<gi, 256, 0, stream>>>(node_feat, mask, emb, W_iou, U_iou,
                                                  hbuf, iou_buf, first, n, d);
        apply_node_k<false><<<16 * n, 256, 0, stream>>>(iou_buf, b_iou, cagg,
                                                        hbuf, cbuf, first, n, d);
    }
    // ---- pool + init ----
    mean_k<<<64, 256, 0, stream>>>(hbuf, mf);
    hidcel_k<<<128, 256, 0, stream>>>(mf, hid_fc_w, hid_fc_b, cell_fc_w, cell_fc_b, hsb, csb);
    // ---- out[0] = 0 ----
    hipMemsetAsync(d_out, 0, (size_t)B_ * V_ * sizeof(float), stream);
    // ---- decoder ----
    for (int t = 1; t < T_; ++t) {
        const float* hs_in  = hsb + ((t - 1) & 1) * (B_ * H_);
        float*       hs_out = hsb + (t & 1) * (B_ * H_);
        lstm_step_k<<<256, 256, 0, stream>>>(emb, W_ih, W_hh, b_ih, b_hh,
                                             pval, pidx, hs_in, hs_out, csb, t);
        logits_k<<<NBL, 256, 0, stream>>>(fc_w, fc_b, hs_out,
                                          out + (size_t)t * B_ * V_, pval, pidx);
    }
}